// Round 10
// baseline (1149.879 us; speedup 1.0000x reference)
//
#include <hip/hip_runtime.h>

#define B_ 8
#define N_ 2048
#define K_ 16
#define M_ (B_*N_)

typedef unsigned long long ull;

__device__ __forceinline__ ull kmin(ull a, ull b) { return a < b ? a : b; }
__device__ __forceinline__ float  fmx(float a, float b)  { return fmaxf(a, b); }
__device__ __forceinline__ double fmx(double a, double b){ return fmax(a, b); }

// ------------------------------------------------------------------
// transpose: X[M][C] -> XT[b][C][N]  (per batch). M_=2^14.
// ------------------------------------------------------------------
__global__ __launch_bounds__(256) void transpose_kernel(const float* __restrict__ X,
                                                        float* __restrict__ XT, int C) {
    int t = blockIdx.x * 256 + threadIdx.x;
    if (t >= M_ * C) return;
    int c = t >> 14;
    int m = t & (M_ - 1);
    int b = m >> 11, n = m & (N_ - 1);
    XT[((size_t)b * C + c) * N_ + n] = X[(size_t)m * C + c];
}

// ------------------------------------------------------------------
// kNN, DIRECT-DIFF (required: fp32 dot-form flips selections vs the
// fp64 reference — rounds 2/9 failed with identical absmax; rounds
// 3/4/6 with direct-diff passed bit-identically).
// Phase A: 32x128 tile, 4x4 register micro-tiles; df=xi-xj, ascending-c
// fmaf chain -> bit-identical distances to the passing rounds.
// S stride 140 (140%32=12): phase-A writes and w-interleaved phase-B
// reads are both 2-words/bank (optimal).
// ------------------------------------------------------------------
template<int C>
__global__ __launch_bounds__(256, 2) void knnD_kernel(const float* __restrict__ XT,
                                                      int* __restrict__ idx_out) {
    constexpr int TJ = 128;
    constexpr int SJ = TJ + 4;    // 132 xjT stride
    constexpr int SS = TJ + 12;   // 140 S stride (bank-optimal both phases)
    __shared__ float xiT[C][36];
    __shared__ float xjT[C][SJ];
    __shared__ float S[32][SS];

    int tid = threadIdx.x;
    int sb = (blockIdx.x & 7) * (M_ / 32 / 8) + (blockIdx.x >> 3);  // XCD swizzle
    int m0 = sb * 32;
    int b  = m0 >> 11;
    int i0 = m0 & (N_ - 1);
    const float* XTb = XT + (size_t)b * C * N_;

    // stage xiT[c][0..31]
    for (int e4 = tid; e4 < C * 8; e4 += 256) {
        int c = e4 >> 3, ch = e4 & 7;
        *(float4*)&xiT[c][ch * 4] = *(const float4*)&XTb[(size_t)c * N_ + i0 + ch * 4];
    }

    ull t[16];
#pragma unroll
    for (int q = 0; q < 16; ++q) t[q] = ~0ull;
    float t15f = __uint_as_float(0x7FFFFFFFu);  // NaN: !(s > t15f) true until full

    int ig = tid >> 5, jl4 = tid & 31;      // phase A: rows ig*4..+3, cols jl4*4..+3
    int irow = tid >> 3, r = tid & 7;       // phase B: row irow, lane r
    int i_loc = i0 + irow;

    for (int jt = 0; jt < N_ / TJ; ++jt) {
        __syncthreads();    // xiT ready (iter 0); prev tile's xjT/S readers done
        // stage xjT (consecutive float4, conflict-free)
        for (int e4 = tid; e4 < C * 32; e4 += 256) {
            int c = e4 >> 5, ch = e4 & 31;
            *(float4*)&xjT[c][ch * 4] =
                *(const float4*)&XTb[(size_t)c * N_ + jt * TJ + ch * 4];
        }
        __syncthreads();

        // phase A: direct-diff accumulation, ascending c (bit-exact vs passing rounds)
        float acc[4][4];
#pragma unroll
        for (int u = 0; u < 4; ++u) {
            acc[u][0] = 0.f; acc[u][1] = 0.f; acc[u][2] = 0.f; acc[u][3] = 0.f;
        }
#pragma unroll 4
        for (int c = 0; c < C; ++c) {
            float4 xi4 = *(const float4*)&xiT[c][ig * 4];
            float4 xj4 = *(const float4*)&xjT[c][jl4 * 4];
            float xiv[4] = {xi4.x, xi4.y, xi4.z, xi4.w};
            float xjv[4] = {xj4.x, xj4.y, xj4.z, xj4.w};
#pragma unroll
            for (int u = 0; u < 4; ++u)
#pragma unroll
                for (int v = 0; v < 4; ++v) {
                    float df = xiv[u] - xjv[v];
                    acc[u][v] = fmaf(df, df, acc[u][v]);
                }
        }
#pragma unroll
        for (int u = 0; u < 4; ++u)
            *(float4*)&S[ig * 4 + u][jl4 * 4] =
                make_float4(acc[u][0], acc[u][1], acc[u][2], acc[u][3]);
        __syncthreads();   // S written

        // phase B: w-interleaved scan (lane r covers j = r*4+32w+e) — set-complete
#pragma unroll
        for (int w = 0; w < 4; ++w) {
            float4 sv = *(const float4*)&S[irow][r * 4 + 32 * w];
            float se[4] = {sv.x, sv.y, sv.z, sv.w};
            float mn = fminf(fminf(se[0], se[1]), fminf(se[2], se[3]));
            if (!(mn > t15f)) {
                int jbase = jt * TJ + r * 4 + 32 * w;
#pragma unroll
                for (int e = 0; e < 4; ++e) {
                    float s = se[e];
                    if (!(s > t15f)) {
                        int jg = jbase + e;
                        if (jg != i_loc) {
                            unsigned uu = __float_as_uint(s) ^ 0x80000000u;  // s>=0
                            ull key = ((ull)uu << 32) | (unsigned)jg;
                            if (key < t[15]) {
                                t[15] = key;
#pragma unroll
                                for (int s2 = 15; s2 > 0; --s2) {
                                    ull a = t[s2 - 1], bb2 = t[s2];
                                    bool sw = bb2 < a;
                                    t[s2 - 1] = sw ? bb2 : a;
                                    t[s2]     = sw ? a : bb2;
                                }
                                t15f = __uint_as_float((unsigned)(t[15] >> 32) ^ 0x80000000u);
                            }
                        }
                    }
                }
            }
        }
    }

    // merge the 8 lanes' sorted-16 lists (bitonic, as in passing rounds)
#pragma unroll
    for (int msk = 1; msk <= 4; msk <<= 1) {
        ull o[16];
#pragma unroll
        for (int q = 0; q < 16; ++q)
            o[q] = __shfl_xor((ull)t[q], msk, 64);
        ull nt[16];
#pragma unroll
        for (int q = 0; q < 16; ++q) nt[q] = kmin(t[q], o[15 - q]);
#pragma unroll
        for (int s2 = 8; s2 >= 1; s2 >>= 1) {
#pragma unroll
            for (int q = 0; q < 16; ++q) {
                if (!(q & s2)) {
                    ull a = nt[q], bb2 = nt[q | s2];
                    bool sw = bb2 < a;
                    nt[q]      = sw ? bb2 : a;
                    nt[q | s2] = sw ? a : bb2;
                }
            }
        }
#pragma unroll
        for (int q = 0; q < 16; ++q) t[q] = nt[q];
    }

    if (r == 0) {
        int* op = idx_out + (size_t)(m0 + irow) * K_;
#pragma unroll
        for (int q = 0; q < 16; ++q) op[q] = (int)(unsigned)(t[q] & 0xffffffffull);
    }
}

// ------------------------------------------------------------------
// proj: T1NB[m][0:DH] = X @ Wtop cols[doff:+DH],
//       T1NB[m][DH:2DH] = X @ Wbot cols[doff:+DH]; f64 acc, TO store.
// ------------------------------------------------------------------
template<int C, typename TO>
__global__ __launch_bounds__(256) void proj_kernel(const float* __restrict__ X,
        const float* __restrict__ W, TO* __restrict__ T1NB,
        int Dfull, int DH, int doff) {
    __shared__ float XsT[C][68];
    __shared__ float Bs[C][64];
    int tid = threadIdx.x;
    int m0 = blockIdx.x * 64;
    int n0 = blockIdx.y * 64;

    if constexpr (C == 3) {
        if (tid < 192) { int row = tid / 3, c = tid - row * 3;
            XsT[c][row] = X[(size_t)(m0 + row) * 3 + c]; }
    } else {
        constexpr int C4 = C / 4;
        for (int e4 = tid; e4 < 64 * C4; e4 += 256) {
            int row = e4 / C4, c4 = e4 - row * C4;
            float4 v = *(const float4*)&X[(size_t)(m0 + row) * C + c4 * 4];
            XsT[c4*4+0][row] = v.x; XsT[c4*4+1][row] = v.y;
            XsT[c4*4+2][row] = v.z; XsT[c4*4+3][row] = v.w;
        }
    }
    for (int e = tid; e < C * 64; e += 256) {
        int c = e >> 6, dc = e & 63;
        int n = n0 + dc;
        float wv = (n < DH) ? W[(size_t)c * Dfull + doff + n]
                            : W[(size_t)(C + c) * Dfull + doff + (n - DH)];
        Bs[c][dc] = wv;
    }
    __syncthreads();

    int tx = tid & 15, ty = tid >> 4;
    double acc[4][4];
#pragma unroll
    for (int u = 0; u < 4; ++u) { acc[u][0]=0.0; acc[u][1]=0.0; acc[u][2]=0.0; acc[u][3]=0.0; }

#pragma unroll 4
    for (int c = 0; c < C; ++c) {
        float4 xv = *(const float4*)&XsT[c][ty * 4];
        float4 wv = *(const float4*)&Bs[c][tx * 4];
        double xd[4] = {(double)xv.x, (double)xv.y, (double)xv.z, (double)xv.w};
        double wd[4] = {(double)wv.x, (double)wv.y, (double)wv.z, (double)wv.w};
#pragma unroll
        for (int u = 0; u < 4; ++u)
#pragma unroll
            for (int v = 0; v < 4; ++v)
                acc[u][v] = fma(xd[u], wd[v], acc[u][v]);
    }
#pragma unroll
    for (int u = 0; u < 4; ++u) {
        TO* dst = &T1NB[(size_t)(m0 + ty * 4 + u) * (2 * DH) + n0 + tx * 4];
        if constexpr (sizeof(TO) == 8) {
            *(double2*)&dst[0] = make_double2(acc[u][0], acc[u][1]);
            *(double2*)&dst[2] = make_double2(acc[u][2], acc[u][3]);
        } else {
            *(float4*)&dst[0] = make_float4((float)acc[u][0], (float)acc[u][1],
                                            (float)acc[u][2], (float)acc[u][3]);
        }
    }
}

// ------------------------------------------------------------------
// gmax: O[m][doff+d] = relu(max_k (T1[m][d] - NB[m][d] + NB[j_k][d]) + b)
// ------------------------------------------------------------------
template<int DH, typename TE>
__global__ __launch_bounds__(256) void gmax_kernel(const TE* __restrict__ T1NB,
        const int* __restrict__ idx, const float* __restrict__ bias,
        float* __restrict__ O, int Dfull, int doff) {
    constexpr int TPP = DH / 2;
    constexpr int PPB = 256 / TPP;
    __shared__ int idxs[PPB * 16];

    int tid = threadIdx.x;
    int cpx = gridDim.x >> 3;
    int sb = ((int)blockIdx.x & 7) * cpx + ((int)blockIdx.x >> 3);  // XCD swizzle
    int m0 = sb * PPB;

    if (tid < PPB * 16)
        idxs[tid] = idx[(size_t)(m0 + tid / 16) * K_ + (tid & 15)];
    __syncthreads();

    int p = tid / TPP, dh = tid % TPP;
    int d0 = dh * 2;
    int m = m0 + p;
    int b = m >> 11;
    size_t base = (size_t)m * (2 * DH);
    TE t1a = T1NB[base + d0],      t1b = T1NB[base + d0 + 1];
    TE nba = T1NB[base + DH + d0], nbb = T1NB[base + DH + d0 + 1];
    TE ba = t1a - nba, bb2 = t1b - nbb;
    TE ma = (TE)-1.0e30, mb = (TE)-1.0e30;
    size_t rowb = ((size_t)(b << 11)) * (2 * DH) + DH + d0;
    const int* ip = &idxs[p * 16];
#pragma unroll 4
    for (int k = 0; k < 16; ++k) {
        int j = ip[k];
        TE qa = T1NB[rowb + (size_t)j * (2 * DH)];
        TE qb = T1NB[rowb + (size_t)j * (2 * DH) + 1];
        ma = fmx(ma, ba + qa);
        mb = fmx(mb, bb2 + qb);
    }
    float2 o;
    o.x = (float)fmx(ma + (TE)bias[doff + d0],     (TE)0);
    o.y = (float)fmx(mb + (TE)bias[doff + d0 + 1], (TE)0);
    *(float2*)&O[(size_t)m * Dfull + doff + d0] = o;
}

// ------------------------------------------------------------------
// reconstructor MLP: 64 -> relu 128 -> relu 64 -> 3.  32 points/block.
// ------------------------------------------------------------------
__global__ __launch_bounds__(256) void recon_kernel(const float* __restrict__ U,
        const float* __restrict__ W0, const float* __restrict__ b0,
        const float* __restrict__ W1, const float* __restrict__ b1,
        const float* __restrict__ W2, const float* __restrict__ b2,
        float* __restrict__ O) {
    __shared__ float F[32 * 68];
    __shared__ float H1[128 * 33];
    __shared__ float H2[64 * 33];
    __shared__ float W2s[64 * 4];
    __shared__ float b0s[128], b1s[64], b2s[4];

    int tid = threadIdx.x;
    int m0 = blockIdx.x * 32;

    {
        const float4* src = (const float4*)(U + (size_t)m0 * 64);
        for (int e4 = tid; e4 < 32 * 16; e4 += 256) {
            int p = e4 >> 4, c4 = e4 & 15;
            *(float4*)&F[p * 68 + c4 * 4] = src[e4];
        }
    }
    if (tid < 192) W2s[(tid / 3) * 4 + (tid % 3)] = W2[tid];
    if (tid < 128) b0s[tid] = b0[tid];
    else if (tid < 192) b1s[tid - 128] = b1[tid - 128];
    else if (tid == 192) { b2s[0] = b2[0]; b2s[1] = b2[1]; b2s[2] = b2[2]; }
    __syncthreads();

    int p = tid >> 3, s = tid & 7;

    float acc[16];
#pragma unroll
    for (int q = 0; q < 16; ++q) acc[q] = 0.f;
    for (int c = 0; c < 64; ++c) {
        float a = F[p * 68 + c];
#pragma unroll
        for (int q = 0; q < 4; ++q) {
            float4 w = *(const float4*)&W0[c * 128 + s * 4 + q * 32];
            acc[q * 4 + 0] = fmaf(a, w.x, acc[q * 4 + 0]);
            acc[q * 4 + 1] = fmaf(a, w.y, acc[q * 4 + 1]);
            acc[q * 4 + 2] = fmaf(a, w.z, acc[q * 4 + 2]);
            acc[q * 4 + 3] = fmaf(a, w.w, acc[q * 4 + 3]);
        }
    }
#pragma unroll
    for (int q = 0; q < 4; ++q)
#pragma unroll
        for (int i2 = 0; i2 < 4; ++i2) {
            int dd = s * 4 + q * 32 + i2;
            H1[dd * 33 + p] = fmaxf(acc[q * 4 + i2] + b0s[dd], 0.f);
        }
    __syncthreads();

    float a2[8];
#pragma unroll
    for (int q = 0; q < 8; ++q) a2[q] = 0.f;
    for (int c = 0; c < 128; ++c) {
        float a = H1[c * 33 + p];
#pragma unroll
        for (int q = 0; q < 2; ++q) {
            float4 w = *(const float4*)&W1[c * 64 + s * 4 + q * 32];
            a2[q * 4 + 0] = fmaf(a, w.x, a2[q * 4 + 0]);
            a2[q * 4 + 1] = fmaf(a, w.y, a2[q * 4 + 1]);
            a2[q * 4 + 2] = fmaf(a, w.z, a2[q * 4 + 2]);
            a2[q * 4 + 3] = fmaf(a, w.w, a2[q * 4 + 3]);
        }
    }
#pragma unroll
    for (int q = 0; q < 2; ++q)
#pragma unroll
        for (int i2 = 0; i2 < 4; ++i2) {
            int dd = s * 4 + q * 32 + i2;
            H2[dd * 33 + p] = fmaxf(a2[q * 4 + i2] + b1s[dd], 0.f);
        }
    __syncthreads();

    if (tid < 96) {
        int p3 = tid / 3, d3 = tid - p3 * 3;
        float av = 0.f;
#pragma unroll
        for (int c = 0; c < 64; ++c)
            av = fmaf(H2[c * 33 + p3], W2s[c * 4 + d3], av);
        O[(size_t)(m0 + p3) * 3 + d3] = av + b2s[d3];
    }
}

// ------------------------------------------------------------------
extern "C" void kernel_launch(void* const* d_in, const int* in_sizes, int n_in,
                              void* d_out, int out_size, void* d_ws, size_t ws_size,
                              hipStream_t stream) {
    const float* x   = (const float*)d_in[0];
    const float* W0  = (const float*)d_in[1];
    const float* b0  = (const float*)d_in[2];
    const float* W1  = (const float*)d_in[3];
    const float* b1  = (const float*)d_in[4];
    const float* W2  = (const float*)d_in[5];
    const float* b2  = (const float*)d_in[6];
    const float* Wup = (const float*)d_in[7];
    const float* bup = (const float*)d_in[8];
    const float* Wr0 = (const float*)d_in[9];
    const float* br0 = (const float*)d_in[10];
    const float* Wr1 = (const float*)d_in[11];
    const float* br1 = (const float*)d_in[12];
    const float* Wr2 = (const float*)d_in[13];
    const float* br2 = (const float*)d_in[14];
    float* out = (float*)d_out;

    char* ws = (char*)d_ws;
    size_t o = 0;
    auto alloc = [&](size_t nbytes) {
        void* pp = ws + o;
        o += (nbytes + 255) & ~(size_t)255;
        return pp;
    };
    float*  X1    = (float*)alloc((size_t)M_ * 32 * 4);
    float*  X2    = (float*)alloc((size_t)M_ * 32 * 4);
    float*  X3    = (float*)alloc((size_t)M_ * 64 * 4);
    float*  H     = (float*)alloc((size_t)M_ * 256 * 4);
    int*    idxb  = (int*)alloc((size_t)M_ * 16 * 4);
    double* T1NBd = (double*)alloc((size_t)M_ * 128 * 8);
    float*  T1NBf = (float*)alloc((size_t)M_ * 256 * 4);
    float*  XT    = (float*)alloc((size_t)M_ * 64 * 4);

    // layer 0 (3 -> 32)
    transpose_kernel<<<(M_ * 3) / 256, 256, 0, stream>>>(x, XT, 3);
    knnD_kernel<3><<<512, 256, 0, stream>>>(XT, idxb);
    proj_kernel<3, double><<<dim3(M_ / 64, 1), 256, 0, stream>>>(x, W0, T1NBd, 32, 32, 0);
    gmax_kernel<32, double><<<M_ / 16, 256, 0, stream>>>(T1NBd, idxb, b0, X1, 32, 0);
    // layer 1 (32 -> 32)
    transpose_kernel<<<(M_ * 32) / 256, 256, 0, stream>>>(X1, XT, 32);
    knnD_kernel<32><<<512, 256, 0, stream>>>(XT, idxb);
    proj_kernel<32, double><<<dim3(M_ / 64, 1), 256, 0, stream>>>(X1, W1, T1NBd, 32, 32, 0);
    gmax_kernel<32, double><<<M_ / 16, 256, 0, stream>>>(T1NBd, idxb, b1, X2, 32, 0);
    // layer 2 (32 -> 64)
    transpose_kernel<<<(M_ * 32) / 256, 256, 0, stream>>>(X2, XT, 32);
    knnD_kernel<32><<<512, 256, 0, stream>>>(XT, idxb);
    proj_kernel<32, double><<<dim3(M_ / 64, 2), 256, 0, stream>>>(X2, W2, T1NBd, 64, 64, 0);
    gmax_kernel<64, double><<<M_ / 8, 256, 0, stream>>>(T1NBd, idxb, b2, X3, 64, 0);
    // NodeShuffle (64 -> 256), fp32 T1NB, two column halves
    transpose_kernel<<<(M_ * 64) / 256, 256, 0, stream>>>(X3, XT, 64);
    knnD_kernel<64><<<512, 256, 0, stream>>>(XT, idxb);
    proj_kernel<64, float><<<dim3(M_ / 64, 4), 256, 0, stream>>>(X3, Wup, T1NBf, 256, 128, 0);
    gmax_kernel<128, float><<<M_ / 4, 256, 0, stream>>>(T1NBf, idxb, bup, H, 256, 0);
    proj_kernel<64, float><<<dim3(M_ / 64, 4), 256, 0, stream>>>(X3, Wup, T1NBf, 256, 128, 128);
    gmax_kernel<128, float><<<M_ / 4, 256, 0, stream>>>(T1NBf, idxb, bup, H, 256, 128);
    // reconstructor
    recon_kernel<<<2048, 256, 0, stream>>>(H, Wr0, br0, Wr1, br1, Wr2, br2, out);
}